// Round 17
// baseline (751.863 us; speedup 1.0000x reference)
//
#include <hip/hip_runtime.h>
#include <cstdint>

// Problem geometry (fixed by the reference)
#define D_IN   4096
#define D_OUT  4096
#define MTOT   16384      // B*S = 8*2048
#define SCALING 2.0f

// GEMM tiling: 256x128 tile, BK=32, 4 waves (2M x 2N), 2 blocks/CU co-resident
#define BM 256
#define BN 128
#define BK 32
#define KT (D_IN / BK)    // 128 K-tiles

#define XBLOCKS ((MTOT * D_IN) / (256 * 8))   // 32768 prep blocks for x
#define WBLOCKS ((D_OUT * D_IN) / (256 * 8))  // 8192 prep blocks for w

typedef float  f32x4  __attribute__((ext_vector_type(4)));
typedef __bf16 bf16x8 __attribute__((ext_vector_type(8)));
typedef unsigned short ushort8 __attribute__((ext_vector_type(8)));
typedef int    int4v  __attribute__((ext_vector_type(4)));
typedef float  float4v __attribute__((ext_vector_type(4)));

// round-to-nearest-even f32 -> bf16
__device__ __forceinline__ unsigned short f2bf(float f) {
  union { float f; unsigned u; } v; v.f = f;
  unsigned r = v.u + 0x7FFF + ((v.u >> 16) & 1);
  return (unsigned short)(r >> 16);
}

// async global->LDS, 16B per lane (wave-uniform base + lane*16 on LDS side)
#define ASYNC16(g, l)                                                        \
  __builtin_amdgcn_global_load_lds(                                          \
      (const __attribute__((address_space(1))) unsigned int*)(g),            \
      (__attribute__((address_space(3))) unsigned int*)(l), 16, 0, 0)

#define BAR    __builtin_amdgcn_s_barrier()
#define VMW(n) asm volatile("s_waitcnt vmcnt(" #n ")" ::: "memory")

// ---------------------------------------------------- fused prep (one launch):
// blocks [0, XBLOCKS):          x f32 -> bf16
// blocks [XBLOCKS, +WBLOCKS):   W_eff = (codes-8)*scale + 2*delta -> bf16
__global__ __launch_bounds__(256) void prep_kernel(const float* __restrict__ x,
                                                   unsigned short* __restrict__ xbf,
                                                   const int* __restrict__ codes,
                                                   const float* __restrict__ scales,
                                                   const float* __restrict__ delta,
                                                   unsigned short* __restrict__ weff) {
  const int bid = blockIdx.x;
  if (bid < XBLOCKS) {
    int i = (bid * 256 + threadIdx.x) * 8;
    float4v lo = *(const float4v*)(x + i);
    float4v hi = *(const float4v*)(x + i + 4);
    ushort8 o;
    o[0] = f2bf(lo[0]); o[1] = f2bf(lo[1]); o[2] = f2bf(lo[2]); o[3] = f2bf(lo[3]);
    o[4] = f2bf(hi[0]); o[5] = f2bf(hi[1]); o[6] = f2bf(hi[2]); o[7] = f2bf(hi[3]);
    *(ushort8*)(xbf + i) = o;
  } else {
    int i = ((bid - XBLOCKS) * 256 + threadIdx.x) * 8;  // 8 elems, same group
    int row = i >> 12;          // / D_IN
    int col = i & (D_IN - 1);
    float s = scales[(row << 6) + (col >> 6)];          // 64 groups per row
    int4v   c0 = *(const int4v*)(codes + i);
    int4v   c1 = *(const int4v*)(codes + i + 4);
    float4v d0 = *(const float4v*)(delta + i);
    float4v d1 = *(const float4v*)(delta + i + 4);
    ushort8 o;
    o[0] = f2bf((float)(c0[0] - 8) * s + SCALING * d0[0]);
    o[1] = f2bf((float)(c0[1] - 8) * s + SCALING * d0[1]);
    o[2] = f2bf((float)(c0[2] - 8) * s + SCALING * d0[2]);
    o[3] = f2bf((float)(c0[3] - 8) * s + SCALING * d0[3]);
    o[4] = f2bf((float)(c1[0] - 8) * s + SCALING * d1[0]);
    o[5] = f2bf((float)(c1[1] - 8) * s + SCALING * d1[1]);
    o[6] = f2bf((float)(c1[2] - 8) * s + SCALING * d1[2]);
    o[7] = f2bf((float)(c1[3] - 8) * s + SCALING * d1[3]);
    *(ushort8*)(weff + i) = o;
  }
}

// ---------------------------------------------------------------- main GEMM
// C[M][N] = Xbf[M][K] * Weff[N][K]^T + bias
// MECHANISM CHANGE vs r12-r16 (all ~50-55% MfmaUtil, single 8-wave block/CU):
// 256x128 tile, 4 waves, BK=32, 48KB LDS -> TWO independent blocks per CU.
// One block's barrier/LDS stalls overlap the other block's MFMA (m114).
// Per-wave geometry unchanged (wave-tile 128x64, acc[8][4]).
//
// LDS layout (keeps the PROVEN 128B-row + XOR-swizzle addressing): logical
// BK=32 rows are 64B, so row-pairs interleave: logical (r, chunk c in 0..3)
// -> physical (R = r mod HALF, cc = c + 4*(r div HALF)), cc ^= (R&7).
// A slot: 128 phys rows (HALF=128), B slot: 64 phys rows (HALF=64).
// Read: lane l, frag f, wave-half w: addr = (f*16+(l&15))*128 +
// (((l>>4)|(w<<2)) ^ (l&7))*16  — identical form to the proven kernel.
// Staging: linear LDS dest (tid*16), inverse-swizzled per-thread global
// source: cc = (t&7)^((t>>3)&7), row += HALF*(cc>>2), colchunk = cc&3.
//
// Schedule (2 single-barrier phases per K-tile, depth-1 dbuf, ALL drain
// windows = 2 phases):
//   P0: stage A(t+1)h01 + B(t+1) (4 ops, buf^1) | vmcnt(6) | BAR |
//       rd A0(4)+B(4) | MM16(m0-3 x n0-3)
//   P1: stage A(t+1)h23 (2 ops, buf^1)          | vmcnt(6) | BAR |
//       rd A1(4)       | MM16(m4-7 x n0-3)
// vmcnt audit (per-thread FIFO, steady state):
//   enter P0: 6 outstanding [t: Ah01,B (4, from t-1 P0); Ah23 (2, t-1 P1)];
//   +4 staged -> 10; vmcnt(6) drains the 4 that P0 reads (Ah01+B). never 0.
//   enter P1: 6; +2 -> 8; vmcnt(6) drains the 2 that P1 reads (Ah23).
// WAR audit (stage at phase-top races only phase p-1 readers, 1 barrier back):
//   P0 stages buf^1.{A rows0-63, B} vs t-1 P1 reads buf^1.A rows64-127 -> disjoint
//   P1 stages buf^1.A rows64-127    vs t   P0 reads buf.{A rows0-63,B} -> disjoint buffer
//   2-phase-back readers are lgkm-drained before crossing the intervening BAR.
// Reg WAR: A regs overwritten at P1 after P0's MMs (in-order); B regs
// overwritten at next P0 after P1's MMs. Safe.
// Tail: tile KT-1 takes vmcnt(2)/vmcnt(0) (queue shrinks 6->2->0).

#define STAGE_A01(buf_, kt_) do {                                            \
    char* d_ = &lds[buf_][0] + tid * 16;                                     \
    const unsigned short* s_ = gA + (size_t)(kt_) * 32;                      \
    ASYNC16(s_, d_);                                                         \
    ASYNC16(s_ + 32 * D_IN, d_ + 4096);                                      \
  } while (0)

#define STAGE_A23(buf_, kt_) do {                                            \
    char* d_ = &lds[buf_][0] + tid * 16 + 8192;                              \
    const unsigned short* s_ = gA + (size_t)(kt_) * 32 + 64 * D_IN;          \
    ASYNC16(s_, d_);                                                         \
    ASYNC16(s_ + 32 * D_IN, d_ + 4096);                                      \
  } while (0)

#define STAGE_B01(buf_, kt_) do {                                            \
    char* d_ = &lds[buf_][0] + tid * 16 + 16384;                             \
    const unsigned short* s_ = gB + (size_t)(kt_) * 32;                      \
    ASYNC16(s_, d_);                                                         \
    ASYNC16(s_ + 32 * D_IN, d_ + 4096);                                      \
  } while (0)

// read A m-half mh_ (4 m-frags; frag f = mh*4+m2 -> phys rows f*16+(l&15))
#define RD_A(buf_, mh_) do {                                                 \
    _Pragma("unroll")                                                        \
    for (int m2 = 0; m2 < 4; ++m2) {                                         \
      const char* p_ = &lds[buf_][0] + ((mh_)*4 + m2) * 2048 + rowb + koffA; \
      A[m2] = *(const bf16x8*)p_;                                            \
    } } while (0)

// read B (4 n-frags; frag n -> phys rows n*16+(l&15) of the 64-row B slot)
#define RD_B(buf_) do {                                                      \
    _Pragma("unroll")                                                        \
    for (int n2 = 0; n2 < 4; ++n2) {                                         \
      const char* p_ = &lds[buf_][0] + 16384 + n2 * 2048 + rowb + koffB;     \
      Bf[n2] = *(const bf16x8*)p_;                                           \
    } } while (0)

// 16 MFMA: A-half mh_ (acc rows mh*4..+3) x all 4 n-frags, K=32
#define MM16(mh_) do {                                                       \
    __builtin_amdgcn_s_setprio(1);                                           \
    _Pragma("unroll")                                                        \
    for (int m2 = 0; m2 < 4; ++m2) {                                         \
      _Pragma("unroll")                                                      \
      for (int n2 = 0; n2 < 4; ++n2) {                                       \
        acc[(mh_)*4 + m2][n2] = __builtin_amdgcn_mfma_f32_16x16x32_bf16(     \
            A[m2], Bf[n2], acc[(mh_)*4 + m2][n2], 0, 0, 0);                  \
      } }                                                                    \
    __builtin_amdgcn_s_setprio(0);                                           \
  } while (0)

// One K-tile. buf_ MUST be literal 0/1. S_ = stage guard; VM0_/VM1_ = vmcnts.
#define KTILE(buf_, g_, S_, VM0_, VM1_) do {                                 \
    /* P0 */                                                                 \
    if (S_) { STAGE_A01((buf_) ^ 1, (g_) + 1); STAGE_B01((buf_) ^ 1, (g_) + 1); } \
    VM0_;                                                                    \
    BAR;                                                                     \
    RD_A(buf_, 0);                                                           \
    RD_B(buf_);                                                              \
    MM16(0);                                                                 \
    /* P1 */                                                                 \
    if (S_) STAGE_A23((buf_) ^ 1, (g_) + 1);                                 \
    VM1_;                                                                    \
    BAR;                                                                     \
    RD_A(buf_, 1);                                                           \
    MM16(1);                                                                 \
  } while (0)

__global__ __launch_bounds__(256, 2) void gemm4_kernel(const unsigned short* __restrict__ xbf,
                                                       const unsigned short* __restrict__ weff,
                                                       const float* __restrict__ bias,
                                                       float* __restrict__ out) {
  __shared__ __attribute__((aligned(1024))) char lds[2][24576];  // 48 KiB

  const int tid  = threadIdx.x;
  const int lane = tid & 63;
  const int wid  = tid >> 6;
  const int wr   = wid >> 1;        // 0..1  (M half: 128 rows)
  const int wc   = wid & 1;         // 0..1  (N half: 64 cols)

  // bijective XCD swizzle: 2048 wgs, 8 XCDs -> each XCD: 8 tm-rows x 32 tn
  const int id  = blockIdx.x;
  const int nid = (id & 7) * 256 + (id >> 3);
  const int tn  = nid & 31;         // N tile (32)
  const int tm  = nid >> 5;         // M tile (64)

  // read lane offsets (swizzled row-pair layout)
  const int rowb  = (lane & 15) * 128;
  const int koffA = ((((lane >> 4) | (wr << 2))) ^ (lane & 7)) << 4;
  const int koffB = ((((lane >> 4) | (wc << 2))) ^ (lane & 7)) << 4;

  // staging lane offsets (inverse-swizzled source)
  const int cc = (tid & 7) ^ ((tid >> 3) & 7);
  const unsigned short* gA = xbf  + (size_t)(tm * BM + (tid >> 3) + 128 * (cc >> 2)) * D_IN + (cc & 3) * 8;
  const unsigned short* gB = weff + (size_t)(tn * BN + (tid >> 3) +  64 * (cc >> 2)) * D_IN + (cc & 3) * 8;

  f32x4 acc[8][4] = {};
  bf16x8 A[4], Bf[4];

  // prologue: tile 0 -> buf0, FIFO order matching the in-loop drains:
  // Ah01, B (drained by tile0-P0's vmcnt(6)), then Ah23 (tile0-P1's).
  STAGE_A01(0, 0);
  STAGE_B01(0, 0);
  STAGE_A23(0, 0);

  for (int g = 0; g < KT - 2; g += 2) {
    KTILE(0, g,     1, VMW(6), VMW(6));
    KTILE(1, g + 1, 1, VMW(6), VMW(6));
  }
  KTILE(0, KT - 2, 1, VMW(6), VMW(6));   // stages tile KT-1
  KTILE(1, KT - 1, 0, VMW(2), VMW(0));   // queue 6 -> drain 4, then 2

  // epilogue: C/D layout col = lane&15, row = (lane>>4)*4 + j  [m89-verified]
  const int row0 = tm * BM + wr * 128 + (lane >> 4) * 4;
  const int col0 = tn * BN + wc * 64 + (lane & 15);
#pragma unroll
  for (int n = 0; n < 4; ++n) {
    const int col = col0 + n * 16;
    const float bv = bias[col];
#pragma unroll
    for (int m = 0; m < 8; ++m) {
      const int r = row0 + m * 16;
#pragma unroll
      for (int j = 0; j < 4; ++j)
        out[(size_t)(r + j) * D_OUT + col] = acc[m][n][j] + bv;
    }
  }
}

extern "C" void kernel_launch(void* const* d_in, const int* in_sizes, int n_in,
                              void* d_out, int out_size, void* d_ws, size_t ws_size,
                              hipStream_t stream) {
  const float* x      = (const float*)d_in[0];
  const int*   codes  = (const int*)d_in[1];
  const float* scales = (const float*)d_in[2];
  const float* bias   = (const float*)d_in[3];
  const float* delta  = (const float*)d_in[4];
  float* out = (float*)d_out;

  unsigned short* xbf  = (unsigned short*)d_ws;                    // 128 MiB
  unsigned short* weff = xbf + (size_t)MTOT * D_IN;                // +32 MiB

  prep_kernel<<<XBLOCKS + WBLOCKS, 256, 0, stream>>>(x, xbf, codes, scales, delta, weff);

  gemm4_kernel<<<(MTOT / BM) * (D_OUT / BN), 256, 0, stream>>>(xbf, weff, bias, out);
}

// Round 18
// 555.166 us; speedup vs baseline: 1.3543x; 1.3543x over previous
//
#include <hip/hip_runtime.h>
#include <cstdint>

// Problem geometry (fixed by the reference)
#define D_IN   4096
#define D_OUT  4096
#define MTOT   16384      // B*S = 8*2048
#define SCALING 2.0f

// GEMM tiling: 256x256 tile, BK=64, 8 waves (2M x 4N), 4 single-barrier phases
#define BM 256
#define BN 256
#define BK 64
#define KT (D_IN / BK)    // 64 K-tiles

#define XBLOCKS ((MTOT * D_IN) / (256 * 8))   // 32768 prep blocks for x
#define WBLOCKS ((D_OUT * D_IN) / (256 * 8))  // 8192 prep blocks for w

typedef float  f32x4  __attribute__((ext_vector_type(4)));
typedef __bf16 bf16x8 __attribute__((ext_vector_type(8)));
typedef unsigned short ushort8 __attribute__((ext_vector_type(8)));
typedef int    int4v  __attribute__((ext_vector_type(4)));
typedef float  float4v __attribute__((ext_vector_type(4)));

// round-to-nearest-even f32 -> bf16
__device__ __forceinline__ unsigned short f2bf(float f) {
  union { float f; unsigned u; } v; v.f = f;
  unsigned r = v.u + 0x7FFF + ((v.u >> 16) & 1);
  return (unsigned short)(r >> 16);
}

// async global->LDS, 16B per lane (wave-uniform base + lane*16 on LDS side)
#define ASYNC16(g, l)                                                        \
  __builtin_amdgcn_global_load_lds(                                          \
      (const __attribute__((address_space(1))) unsigned int*)(g),            \
      (__attribute__((address_space(3))) unsigned int*)(l), 16, 0, 0)

#define BAR    __builtin_amdgcn_s_barrier()
#define VMW(n) asm volatile("s_waitcnt vmcnt(" #n ")" ::: "memory")

// ---------------------------------------------------- fused prep (one launch):
// blocks [0, XBLOCKS):          x f32 -> bf16
// blocks [XBLOCKS, +WBLOCKS):   W_eff = (codes-8)*scale + 2*delta -> bf16
__global__ __launch_bounds__(256) void prep_kernel(const float* __restrict__ x,
                                                   unsigned short* __restrict__ xbf,
                                                   const int* __restrict__ codes,
                                                   const float* __restrict__ scales,
                                                   const float* __restrict__ delta,
                                                   unsigned short* __restrict__ weff) {
  const int bid = blockIdx.x;
  if (bid < XBLOCKS) {
    int i = (bid * 256 + threadIdx.x) * 8;
    float4v lo = *(const float4v*)(x + i);
    float4v hi = *(const float4v*)(x + i + 4);
    ushort8 o;
    o[0] = f2bf(lo[0]); o[1] = f2bf(lo[1]); o[2] = f2bf(lo[2]); o[3] = f2bf(lo[3]);
    o[4] = f2bf(hi[0]); o[5] = f2bf(hi[1]); o[6] = f2bf(hi[2]); o[7] = f2bf(hi[3]);
    *(ushort8*)(xbf + i) = o;
  } else {
    int i = ((bid - XBLOCKS) * 256 + threadIdx.x) * 8;  // 8 elems, same group
    int row = i >> 12;          // / D_IN
    int col = i & (D_IN - 1);
    float s = scales[(row << 6) + (col >> 6)];          // 64 groups per row
    int4v   c0 = *(const int4v*)(codes + i);
    int4v   c1 = *(const int4v*)(codes + i + 4);
    float4v d0 = *(const float4v*)(delta + i);
    float4v d1 = *(const float4v*)(delta + i + 4);
    ushort8 o;
    o[0] = f2bf((float)(c0[0] - 8) * s + SCALING * d0[0]);
    o[1] = f2bf((float)(c0[1] - 8) * s + SCALING * d0[1]);
    o[2] = f2bf((float)(c0[2] - 8) * s + SCALING * d0[2]);
    o[3] = f2bf((float)(c0[3] - 8) * s + SCALING * d0[3]);
    o[4] = f2bf((float)(c1[0] - 8) * s + SCALING * d1[0]);
    o[5] = f2bf((float)(c1[1] - 8) * s + SCALING * d1[1]);
    o[6] = f2bf((float)(c1[2] - 8) * s + SCALING * d1[2]);
    o[7] = f2bf((float)(c1[3] - 8) * s + SCALING * d1[3]);
    *(ushort8*)(weff + i) = o;
  }
}

// ---------------------------------------------------------------- main GEMM
// C[M][N] = Xbf[M][K] * Weff[N][K]^T + bias
// BEST-MEASURED configuration (r12/r14: 463-472 us, MfmaUtil 54.6-56.3%):
// 4 single-barrier phases per K-tile:
//   P0: stage A(g+1)h0 | BAR | rd A0(8)+B0(4), MM16(A0,B0)
//   P1: stage A(g+1)h1 | BAR | rd B1(4),       MM16(A0,B1)
//   P2: stage B(g+2)h0 | BAR | rd A1(8),       MM16(A1,B0)
//   P3: stage B(g+2)h1 | BAR |                 MM16(A1,B1) | vmcnt(4)
// Single-barrier WAR audit (waves at most ONE phase apart; a STAGE at
// phase-top only races phase p-1 readers):
//   P0 stages buf^1.A0 : P3 reads nothing            -> safe
//   P1 stages buf^1.A1 : P0 reads buf slots only     -> safe
//   P2 stages buf.B0   : P1 reads buf.B1 only        -> safe
//   P3 stages buf.B1   : P2 reads buf.A1 only        -> safe
// Each wave's ds_reads are lgkm-drained by its own MM16 before it reaches the
// next barrier. Whole-tile drain (round-8 lesson: all 4 slots are read at P0
// by wave-dependent slot selects): vmcnt(4) at tile end, queue = B(g+1)x4,
// A(g+1)x4, B(g+2)x4 = 12 -> drains tile g+1 fully, leaves B(g+2) (never 0).
// LDS slots/buf: [A0 rows0-127][A1][B0][B1], each [128][64] bf16, XOR-swizzled
// byte ^= ((row&7)<<4): inverse-swizzled global source + swizzled ds_read.
// Loop unrolled x2 so buf is a LITERAL (immediate-offset folding).
//
// Exploration record (rounds 2-17): 8-barrier variants 480-513; frag-dbuf
// spilled (620); 32x32x16 MFMA 4-way bank conflicts (568); 2-barrier merge
// 473 (FETCH +18%); P3-prefetch 470 (neutral); 256x128 2-block/CU 700
// (FETCH 2x, occupancy unchanged). This 4-phase point is the optimum.

#define STAGE_A(buf_, kt_, h_) do {                                          \
    char* d_ = &lds[buf_][h_][0] + tid * 16;                                 \
    const unsigned short* s_ = gA + (size_t)(h_) * 128 * D_IN + (kt_) * 64;  \
    ASYNC16(s_, d_);                                                         \
    ASYNC16(s_ + 64 * D_IN, d_ + 8192);                                      \
  } while (0)

#define STAGE_B(buf_, kt_, h_) do {                                          \
    char* d_ = &lds[buf_][2 + (h_)][0] + tid * 16;                           \
    const unsigned short* s_ = gB + (size_t)(h_) * 128 * D_IN + (kt_) * 64;  \
    ASYNC16(s_, d_);                                                         \
    ASYNC16(s_ + 64 * D_IN, d_ + 8192);                                      \
  } while (0)

// read A-half h_ (4 m-frags, rows h*64..h*64+63 of wave's panel) -> A[4][2]
#define RD_A(buf_, h_) do {                                                  \
    _Pragma("unroll")                                                        \
    for (int m2 = 0; m2 < 4; ++m2) {                                         \
      const char* p_ = &lds[buf_][wr][0] + ((h_)*4 + m2) * 2048 + rowb;      \
      A[m2][0] = *(const bf16x8*)(p_ + koff0);                               \
      A[m2][1] = *(const bf16x8*)(p_ + koff1);                               \
    } } while (0)

// read B-half h_ (2 n-frags) of the wave's 64-col B panel
#define RD_B(buf_, h_, dst_) do {                                            \
    _Pragma("unroll")                                                        \
    for (int n2 = 0; n2 < 2; ++n2) {                                         \
      const char* p_ = &lds[buf_][2 + (wc >> 1)][0] + (wc & 1) * 8192 +      \
                       (h_) * 4096 + n2 * 2048 + rowb;                       \
      dst_[n2][0] = *(const bf16x8*)(p_ + koff0);                            \
      dst_[n2][1] = *(const bf16x8*)(p_ + koff1);                            \
    } } while (0)

// 16 MFMA: A-half (acc rows mh*4..+3) x B-half (acc cols nh*2..+1), K=64
#define MM16(bfr_, mh_, nh_) do {                                            \
    __builtin_amdgcn_s_setprio(1);                                           \
    _Pragma("unroll")                                                        \
    for (int m2 = 0; m2 < 4; ++m2) {                                         \
      _Pragma("unroll")                                                      \
      for (int n2 = 0; n2 < 2; ++n2) {                                       \
        acc[(mh_)*4 + m2][(nh_)*2 + n2] = __builtin_amdgcn_mfma_f32_16x16x32_bf16( \
            A[m2][0], bfr_[n2][0], acc[(mh_)*4 + m2][(nh_)*2 + n2], 0, 0, 0);      \
        acc[(mh_)*4 + m2][(nh_)*2 + n2] = __builtin_amdgcn_mfma_f32_16x16x32_bf16( \
            A[m2][1], bfr_[n2][1], acc[(mh_)*4 + m2][(nh_)*2 + n2], 0, 0, 0);      \
      } }                                                                    \
    __builtin_amdgcn_s_setprio(0);                                           \
  } while (0)

// One K-tile. buf_ MUST be literal 0/1. SA_/SB_ compile-time guards;
// VM_ is the vmcnt statement at tile end (after MM_P3).
#define KTILE(buf_, g_, SA_, SB_, VM_) do {                                  \
    /* P0 */                                                                 \
    if (SA_) STAGE_A((buf_) ^ 1, (g_) + 1, 0);                               \
    BAR;                                                                     \
    RD_A(buf_, 0);                                                           \
    RD_B(buf_, 0, B0);                                                       \
    MM16(B0, 0, 0);                                                          \
    /* P1 */                                                                 \
    if (SA_) STAGE_A((buf_) ^ 1, (g_) + 1, 1);                               \
    BAR;                                                                     \
    RD_B(buf_, 1, B1);                                                       \
    MM16(B1, 0, 1);                                                          \
    /* P2 */                                                                 \
    if (SB_) STAGE_B(buf_, (g_) + 2, 0);                                     \
    BAR;                                                                     \
    RD_A(buf_, 1);                                                           \
    MM16(B0, 1, 0);                                                          \
    /* P3 */                                                                 \
    if (SB_) STAGE_B(buf_, (g_) + 2, 1);                                     \
    BAR;                                                                     \
    MM16(B1, 1, 1);                                                          \
    VM_;                                                                     \
  } while (0)

__global__ __launch_bounds__(512, 2) void gemm8_kernel(const unsigned short* __restrict__ xbf,
                                                       const unsigned short* __restrict__ weff,
                                                       const float* __restrict__ bias,
                                                       float* __restrict__ out) {
  __shared__ __attribute__((aligned(1024))) char lds[2][4][16384];  // 128 KiB

  const int tid  = threadIdx.x;
  const int lane = tid & 63;
  const int wid  = tid >> 6;
  const int wr   = wid >> 2;        // 0..1  (M half)
  const int wc   = wid & 3;         // 0..3  (N quarter)

  // bijective XCD swizzle: 1024 wgs, 8 XCDs -> each XCD gets 8 M-rows x 16 N-cols
  const int id  = blockIdx.x;
  const int nid = (id & 7) * 128 + (id >> 3);
  const int tn  = nid & 15;         // N tile (16)
  const int tm  = nid >> 4;         // M tile (64)

  // ds_read lane offsets (swizzled): addr = row*128 + ((kk*64 + (l>>4)*16) ^ ((l&7)<<4))
  const int rowb  = (lane & 15) * 128;
  const int kx    = (lane & 7) << 4;
  const int koff0 = (((lane >> 4) * 16) ^ kx);
  const int koff1 = ((64 + (lane >> 4) * 16) ^ kx);

  // staging lane offsets (inverse-swizzled source)
  const int sr = tid >> 3;                        // row within 64-row chunk
  const int ke = ((tid & 7) ^ (sr & 7)) * 8;      // permuted k-element offset
  const unsigned short* gA = xbf  + (size_t)(tm * BM + sr) * D_IN + ke;
  const unsigned short* gB = weff + (size_t)(tn * BN + sr) * D_IN + ke;

  f32x4 acc[8][4] = {};
  bf16x8 A[4][2], B0[2][2], B1[2][2];

  // prologue: tile 0 (A+B) -> buf0 ; B of tile 1 -> buf1  (12 loads)
  STAGE_A(0, 0, 0); STAGE_A(0, 0, 1);
  STAGE_B(0, 0, 0); STAGE_B(0, 0, 1);
  STAGE_B(1, 1, 0); STAGE_B(1, 1, 1);
  VMW(4);           // tile 0 fully landed; B(1)x4 stays in flight
                    // (tile 0's P0 barrier is the release point for all waves)

  for (int g = 0; g < KT - 2; g += 2) {
    KTILE(0, g,     1, 1, VMW(4));
    KTILE(1, g + 1, 1, 1, VMW(4));
  }
  // tile KT-2 (buf0): stages A(KT-1) only; end queue = B(KT-1)x4 + A(KT-1)x4
  //   -> full drain so tile KT-1 is complete before its P0 reads.
  KTILE(0, KT - 2, 1, 0, VMW(0));
  // tile KT-1 (buf1): pure compute
  KTILE(1, KT - 1, 0, 0, (void)0);

  // epilogue: C/D layout col = lane&15, row = (lane>>4)*4 + j  [m89-verified]
  const int row0 = tm * BM + wr * 128 + (lane >> 4) * 4;
  const int col0 = tn * BN + wc * 64 + (lane & 15);
#pragma unroll
  for (int n = 0; n < 4; ++n) {
    const int col = col0 + n * 16;
    const float bv = bias[col];
#pragma unroll
    for (int m = 0; m < 8; ++m) {
      const int r = row0 + m * 16;
#pragma unroll
      for (int j = 0; j < 4; ++j)
        out[(size_t)(r + j) * D_OUT + col] = acc[m][n][j] + bv;
    }
  }
}

extern "C" void kernel_launch(void* const* d_in, const int* in_sizes, int n_in,
                              void* d_out, int out_size, void* d_ws, size_t ws_size,
                              hipStream_t stream) {
  const float* x      = (const float*)d_in[0];
  const int*   codes  = (const int*)d_in[1];
  const float* scales = (const float*)d_in[2];
  const float* bias   = (const float*)d_in[3];
  const float* delta  = (const float*)d_in[4];
  float* out = (float*)d_out;

  unsigned short* xbf  = (unsigned short*)d_ws;                    // 128 MiB
  unsigned short* weff = xbf + (size_t)MTOT * D_IN;                // +32 MiB

  prep_kernel<<<XBLOCKS + WBLOCKS, 256, 0, stream>>>(x, xbf, codes, scales, delta, weff);

  gemm8_kernel<<<(MTOT / BM) * (D_OUT / BN), 512, 0, stream>>>(xbf, weff, bias, out);
}